// Round 5
// baseline (65.471 us; speedup 1.0000x reference)
//
#include <hip/hip_runtime.h>

typedef float f32x4 __attribute__((ext_vector_type(4)));
typedef short s16x8 __attribute__((ext_vector_type(8)));

#if __has_builtin(__builtin_amdgcn_exp2f)
#define EXP2F(x) __builtin_amdgcn_exp2f(x)
#else
#define EXP2F(x) __expf((x) * 0.6931471805599453f)
#endif

__device__ inline unsigned short bf16_rne(float v) {
    unsigned u = __float_as_uint(v);
    u += 0x7FFFu + ((u >> 16) & 1u);
    return (unsigned short)(u >> 16);
}

// Prologue: nrm[r] = -g*log2e*|row|^2 for x rows then y rows.
__global__ __launch_bounds__(256) void rbf_norms(
        const float* __restrict__ x, const float* __restrict__ y,
        const float* __restrict__ gamma_p, float* __restrict__ nrm,
        int N, int M) {
    const int t = threadIdx.x;
    const int r = blockIdx.x * 16 + (t >> 4);
    const int c = (t & 15) << 2;
    if (r >= N + M) return;
    const float* src = ((r < N) ? (x + (size_t)r * 64) : (y + (size_t)(r - N) * 64)) + c;
    f32x4 v = *(const f32x4*)src;
    float s = v[0]*v[0] + v[1]*v[1] + v[2]*v[2] + v[3]*v[3];
    s += __shfl_xor(s, 1);
    s += __shfl_xor(s, 2);
    s += __shfl_xor(s, 4);
    s += __shfl_xor(s, 8);
    if ((t & 15) == 0)
        nrm[r] = -(*gamma_p) * 1.4426950408889634f * s;
}

// Main: out[i,j] = exp2( nx[i] + ny[j] + two_s * (x_i . y_j) )
// 128x128 tile / 256-thread block, 4 waves 2x2.
// Panels staged into LDS once per block directly from fp32 (inline bf16
// hi/lo split), XOR-swizzled; shared by all 4 waves.
// Epilogue: per-wave LDS transpose bounce (overlaid on dead staging buffer)
// -> every global store is nontemporal dwordx4 = 4 rows x 256B full lines.
#define LROW 68
__global__ __launch_bounds__(256, 2) void rbf_main(
        const float* __restrict__ x, const float* __restrict__ y,
        const float* __restrict__ gamma_p, const float* __restrict__ nrm,
        float* __restrict__ out, int N, int M, int nbm, int nbn) {
    __shared__ char smem[65536];   // Ah@0 Al@16K Bh@32K Bl@48K; epilogue overlay

    // XCD-chunked bijective swizzle (HW round-robins blockIdx -> XCD):
    // XCD k owns 8 contiguous x-panels; bn-major within the chunk.
    int bm, bn;
    const int nwg = nbm * nbn;
    if ((nwg & 7) == 0 && (nbm & 7) == 0) {
        const int xcd = blockIdx.x & 7;
        const int lo  = blockIdx.x >> 3;
        const int bmPerX = nbm >> 3;
        bn = lo / bmPerX;
        bm = xcd * bmPerX + (lo - bn * bmPerX);
    } else {
        bm = blockIdx.x / nbn;
        bn = blockIdx.x - bm * nbn;
    }

    const int tid = threadIdx.x;
    const int lane = tid & 63;
    const int wid = tid >> 6;
    const int wr = wid >> 1, wc = wid & 1;
    const int brow = bm * 128 + wr * 64;
    const int bcol = bn * 128 + wc * 64;
    const int l15 = lane & 15;
    const int lg  = lane >> 4;          // 0..3

    f32x4 acc[4][4];
    #pragma unroll
    for (int i = 0; i < 4; ++i)
        #pragma unroll
        for (int j = 0; j < 4; ++j)
            #pragma unroll
            for (int e = 0; e < 4; ++e)
                acc[i][j][e] = 0.0f;

    // --- stage panels: fp32 -> inline bf16 hi/lo split -> swizzled LDS ---
    // unit u (8 floats = 32B src, 16B hi + 16B lo dst):
    //   u<1024: x panel, else y panel; v=u&1023, row=v>>3, kc=v&7
    //   hi byte = base + row*128 + ((kc ^ (row&7))<<4), lo at +16384
    {
        const float* srcx = x + (size_t)bm * 128 * 64;
        const float* srcy = y + (size_t)bn * 128 * 64;
        #pragma unroll
        for (int it = 0; it < 8; ++it) {
            const int u = it * 256 + tid;
            const int isy = it >> 2;             // compile-time
            const int v = u & 1023;
            const int row = v >> 3, kc = v & 7;
            const float* s = (isy ? srcy : srcx) + (size_t)row * 64 + kc * 8;
            f32x4 t0 = *(const f32x4*)s;
            f32x4 t1 = *(const f32x4*)(s + 4);
            s16x8 h, l;
            #pragma unroll
            for (int j = 0; j < 4; ++j) {
                unsigned short hb = bf16_rne(t0[j]);
                float hf = __uint_as_float((unsigned)hb << 16);
                h[j] = (short)hb; l[j] = (short)bf16_rne(t0[j] - hf);
                hb = bf16_rne(t1[j]);
                hf = __uint_as_float((unsigned)hb << 16);
                h[4+j] = (short)hb; l[4+j] = (short)bf16_rne(t1[j] - hf);
            }
            const int dst = (isy << 15) + row * 128 + ((kc ^ (row & 7)) << 4);
            *(s16x8*)(smem + dst) = h;
            *(s16x8*)(smem + dst + 16384) = l;
        }
    }
    __syncthreads();

    s16x8 ah[4], al[4], bh[4], bl[4];
    #pragma unroll
    for (int k0 = 0; k0 < 64; k0 += 32) {
        const int kc = (k0 >> 3) + lg;
        #pragma unroll
        for (int mf = 0; mf < 4; ++mf) {
            const int arow = wr * 64 + mf * 16 + l15;
            const int off = arow * 128 + ((kc ^ (arow & 7)) << 4);
            ah[mf] = *(const s16x8*)(smem + off);
            al[mf] = *(const s16x8*)(smem + 16384 + off);
        }
        #pragma unroll
        for (int nf = 0; nf < 4; ++nf) {
            const int brw = wc * 64 + nf * 16 + l15;
            const int off = brw * 128 + ((kc ^ (brw & 7)) << 4);
            bh[nf] = *(const s16x8*)(smem + 32768 + off);
            bl[nf] = *(const s16x8*)(smem + 49152 + off);
        }
        #pragma unroll
        for (int mf = 0; mf < 4; ++mf)
            #pragma unroll
            for (int nf = 0; nf < 4; ++nf) {
                acc[mf][nf] = __builtin_amdgcn_mfma_f32_16x16x32_bf16(ah[mf], bh[nf], acc[mf][nf], 0, 0, 0);
                acc[mf][nf] = __builtin_amdgcn_mfma_f32_16x16x32_bf16(ah[mf], bl[nf], acc[mf][nf], 0, 0, 0);
                acc[mf][nf] = __builtin_amdgcn_mfma_f32_16x16x32_bf16(al[mf], bh[nf], acc[mf][nf], 0, 0, 0);
            }
    }
    __syncthreads();   // staging buffer dead; safe to overlay epilogue bounce

    const float g = *gamma_p;
    const float two_s = 2.0f * g * 1.4426950408889634f;
    const float* nx = nrm;
    const float* ny = nrm + N;

    float yn[4];
    #pragma unroll
    for (int nf = 0; nf < 4; ++nf)
        yn[nf] = ny[bcol + nf * 16 + l15];

    float* wl = (float*)smem + wid * 16 * LROW;   // per-wave 4.25KB overlay

    #pragma unroll
    for (int mf = 0; mf < 4; ++mf) {
        // C/D layout: col = lane&15 (within 16), row = lg*4 + j
        float xn[4];
        #pragma unroll
        for (int j = 0; j < 4; ++j)
            xn[j] = nx[brow + mf * 16 + lg * 4 + j];

        #pragma unroll
        for (int nf = 0; nf < 4; ++nf) {
            const int c = nf * 16 + l15;
            #pragma unroll
            for (int j = 0; j < 4; ++j) {
                const float d = fmaf(two_s, acc[mf][nf][j], xn[j] + yn[nf]);
                wl[(lg * 4 + j) * LROW + c] = EXP2F(d);
            }
        }
        // same-wave exchange: lgkmcnt ordering only, no barrier needed
        #pragma unroll
        for (int t = 0; t < 4; ++t) {
            const int r = t * 4 + lg;
            f32x4 v = *(const f32x4*)&wl[r * LROW + l15 * 4];
            float* dst = out + (size_t)(brow + mf * 16 + r) * M + bcol + l15 * 4;
            __builtin_nontemporal_store(v, (f32x4*)dst);
        }
    }
}

extern "C" void kernel_launch(void* const* d_in, const int* in_sizes, int n_in,
                              void* d_out, int out_size, void* d_ws, size_t ws_size,
                              hipStream_t stream) {
    const float* x = (const float*)d_in[0];
    const float* y = (const float*)d_in[1];
    const float* gamma_p = (const float*)d_in[2];
    float* out = (float*)d_out;
    float* nrm = (float*)d_ws;          // (N+M) floats

    const int D = 64;
    const int N = in_sizes[0] / D;
    const int M = in_sizes[1] / D;

    const int rows = N + M;
    rbf_norms<<<(rows + 15) / 16, 256, 0, stream>>>(x, y, gamma_p, nrm, N, M);

    const int nbm = N / 128, nbn = M / 128;
    rbf_main<<<nbm * nbn, 256, 0, stream>>>(x, y, gamma_p, nrm, out, N, M, nbm, nbn);
}